// Round 15
// baseline (232.281 us; speedup 1.0000x reference)
//
#include <hip/hip_runtime.h>

typedef unsigned short u16;
typedef unsigned int   u32;
typedef __attribute__((ext_vector_type(8))) short bf16x8;
typedef __attribute__((ext_vector_type(4))) float f32x4;

#define BB   8
#define CIN  256
#define NT   256
#define EMB  512
#define NH   8

// ---- bf16 <-> f32 via raw bits ----
__device__ __forceinline__ float bf2f(u16 b) {
    union { u32 u; float f; } v; v.u = ((u32)b) << 16; return v.f;
}
__device__ __forceinline__ u16 f2bf(float f) {
    union { float f; u32 u; } v; v.f = f;
    u32 r = v.u + 0x7FFFu + ((v.u >> 16) & 1u);  // RNE
    return (u16)(r >> 16);
}
__device__ __forceinline__ float ld(const u16* base, size_t idx, int f32) {
    return f32 ? ((const float*)base)[idx] : bf2f(base[idx]);
}

struct alignas(16) U32x4 { u32 x, y, z, w; };

// acc[r*S + c] += a4[r] * b4[c]
#define FMA44(AP, S, A4, B4) do { \
  (AP)[0*(S)+0] += (A4).x*(B4).x; (AP)[0*(S)+1] += (A4).x*(B4).y; (AP)[0*(S)+2] += (A4).x*(B4).z; (AP)[0*(S)+3] += (A4).x*(B4).w; \
  (AP)[1*(S)+0] += (A4).y*(B4).x; (AP)[1*(S)+1] += (A4).y*(B4).y; (AP)[1*(S)+2] += (A4).y*(B4).z; (AP)[1*(S)+3] += (A4).y*(B4).w; \
  (AP)[2*(S)+0] += (A4).z*(B4).x; (AP)[2*(S)+1] += (A4).z*(B4).y; (AP)[2*(S)+2] += (A4).z*(B4).z; (AP)[2*(S)+3] += (A4).z*(B4).w; \
  (AP)[3*(S)+0] += (A4).w*(B4).x; (AP)[3*(S)+1] += (A4).w*(B4).y; (AP)[3*(S)+2] += (A4).w*(B4).z; (AP)[3*(S)+3] += (A4).w*(B4).w; \
} while (0)

// ---------------- K0: dtype detector (flag=1 means fp32 inputs) ----------------
__global__ void k_detect(const u16* __restrict__ x1, int* __restrict__ flag) {
    __shared__ int cnt;
    if (threadIdx.x == 0) cnt = 0;
    __syncthreads();
    int t = threadIdx.x;
    int local = 0;
    for (int j = t * 16; j < t * 16 + 16; j += 2) {
        u16 w = x1[j];
        int e = (w >> 7) & 0xFF;
        if (e >= 100 && e <= 145) local++;
    }
    atomicAdd(&cnt, local);
    __syncthreads();
    if (t == 0) *flag = (cnt >= 1200) ? 0 : 1;
}

// ---------------- K1: QKV projections (scalar, pipelined) ----------------------
// Q,K: [h][b][n][c64] (c contig);  V: [h][b][c64][n] (n contig)
__global__ void k_qkv(
    const u16* __restrict__ x1, const u16* __restrict__ x2,
    const u16* __restrict__ Wq, const u16* __restrict__ bq,
    const u16* __restrict__ Wk, const u16* __restrict__ bk,
    const u16* __restrict__ Wv, const u16* __restrict__ bv,
    u16* __restrict__ Qg, u16* __restrict__ Kg, u16* __restrict__ Vg,
    const int* __restrict__ flag)
{
    const int f32 = *flag;
    int id = blockIdx.x;
    int proj = id >> 8;            // 0=q,1=k,2=v
    int rem  = id & 255;
    int b  = rem >> 5;
    int ot = (rem >> 2) & 7;       // o-tile (64 outputs = 8 c x 8 h)
    int nt = rem & 3;              // n-tile (64 tokens)

    const u16* X    = (proj == 0) ? x1 : x2;
    const u16* W    = (proj == 0) ? Wq : (proj == 1) ? Wk : Wv;
    const u16* bias = (proj == 0) ? bq : (proj == 1) ? bk : bv;

    __shared__ float Ws[64][68];   // stage: Ws[i][o]; epilogue: Ls[o_local][n_local]
    __shared__ float Xs[64][64];   // Xs[i][n]

    int t = threadIdx.x;
    int lane64 = t & 63;
    int quad   = t >> 6;
    int og = t >> 4;
    int ng = t & 15;

    float acc[16];
#pragma unroll
    for (int j = 0; j < 16; ++j) acc[j] = 0.f;

    float wreg[16], xreg[16];
#pragma unroll
    for (int p = 0; p < 16; ++p) {
        int o = quad + 4*p;
        wreg[p] = ld(W, (size_t)(ot*64 + o)*CIN + 0*64 + lane64, f32);
    }
#pragma unroll
    for (int p = 0; p < 16; ++p) {
        int i = quad + 4*p;
        xreg[p] = ld(X, ((size_t)b*CIN + 0*64 + i)*NT + nt*64 + lane64, f32);
    }

    for (int kc = 0; kc < 4; ++kc) {
        __syncthreads();
#pragma unroll
        for (int p = 0; p < 16; ++p)
            Ws[lane64][quad + 4*p] = wreg[p];
#pragma unroll
        for (int p = 0; p < 16; ++p)
            Xs[quad + 4*p][lane64] = xreg[p];
        __syncthreads();

        if (kc < 3) {
            int kn = kc + 1;
#pragma unroll
            for (int p = 0; p < 16; ++p) {
                int o = quad + 4*p;
                wreg[p] = ld(W, (size_t)(ot*64 + o)*CIN + kn*64 + lane64, f32);
            }
#pragma unroll
            for (int p = 0; p < 16; ++p) {
                int i = quad + 4*p;
                xreg[p] = ld(X, ((size_t)b*CIN + kn*64 + i)*NT + nt*64 + lane64, f32);
            }
        }

#pragma unroll 8
        for (int i = 0; i < 64; ++i) {
            float4 w4 = *(const float4*)&Ws[i][og*4];
            float4 x4 = *(const float4*)&Xs[i][ng*4];
            FMA44(acc, 4, w4, x4);
        }
    }
    __syncthreads();

    // ---- epilogue ----
#pragma unroll
    for (int jo = 0; jo < 4; ++jo) {
        int o = ot*64 + og*4 + jo;
        float bb = ld(bias, o, f32);
#pragma unroll
        for (int jn = 0; jn < 4; ++jn)
            Ws[og*4 + jo][ng*4 + jn] = acc[jo*4 + jn] + bb;
    }
    __syncthreads();

    if (proj < 2) {
        u16* OUT = (proj == 0) ? Qg : Kg;
        int hh = t >> 5;
        int nb = t & 31;
#pragma unroll
        for (int p = 0; p < 2; ++p) {
            int nn = nb + 32*p;
            u32 pk[4];
#pragma unroll
            for (int e = 0; e < 4; ++e) {
                u16 lo = f2bf(Ws[(2*e  )*8 + hh][nn]);
                u16 hi = f2bf(Ws[(2*e+1)*8 + hh][nn]);
                pk[e] = (u32)lo | ((u32)hi << 16);
            }
            U32x4 v; v.x = pk[0]; v.y = pk[1]; v.z = pk[2]; v.w = pk[3];
            *(U32x4*)&OUT[((size_t)((hh*8 + b)*256) + nt*64 + nn)*64 + ot*8] = v;
        }
    } else {
        int rr = t >> 2;
        int hh = rr & 7, cl = rr >> 3;
        int nq = t & 3;
        u32 pk[8];
#pragma unroll
        for (int e = 0; e < 8; ++e) {
            u16 lo = f2bf(Ws[cl*8 + hh][nq*16 + 2*e  ]);
            u16 hi = f2bf(Ws[cl*8 + hh][nq*16 + 2*e+1]);
            pk[e] = (u32)lo | ((u32)hi << 16);
        }
        size_t base = ((size_t)((hh*8 + b)*64) + ot*8 + cl)*256 + nt*64 + nq*16;
        U32x4 v0; v0.x = pk[0]; v0.y = pk[1]; v0.z = pk[2]; v0.w = pk[3];
        U32x4 v1; v1.x = pk[4]; v1.y = pk[5]; v1.z = pk[6]; v1.w = pk[7];
        *(U32x4*)&Vg[base]     = v0;
        *(U32x4*)&Vg[base + 8] = v1;
    }
}

// ---------------- K2: cross-batch attention, MFMA, kb-split(2) -----------------
// ONLY MFMA kernel in the module. Changes vs R14 green: grid 256 -> 512
// (kbh = bid&1), each block loops 4 key-batches and writes an fp32 PARTIAL
// O to its half of Opart (same [h][b][n][c] formula, offset by kbh). Halves
// the serial latency chain and doubles blocks/CU. Partials summed by scalar
// k_osum (per-key-batch softmax makes halves exactly summable).
__global__ __launch_bounds__(256) void k_attn(
    const u16* __restrict__ Qg, const u16* __restrict__ Kg,
    const u16* __restrict__ Vg, float* __restrict__ Opart)
{
    int bid = blockIdx.x;
    int h   = bid >> 6;
    int b   = (bid >> 3) & 7;
    int ntq = (bid >> 1) & 3;
    int kbh = bid & 1;

    int t = threadIdx.x;
    int l = t & 63, w = t >> 6;
    int quad = l >> 4, col = l & 15;

    __shared__ __align__(16) u16 S[16896];   // 33 KB, phases: K | P(stride 66) | V

    int q = ntq*64 + w*16 + col;
    const size_t qrow = ((size_t)(h*8 + b)*256 + q)*64;
    bf16x8 qf0 = *(const bf16x8*)&Qg[qrow +  0 + quad*8];
    bf16x8 qf1 = *(const bf16x8*)&Qg[qrow + 32 + quad*8];

    f32x4 Oacc[4];
#pragma unroll
    for (int ct = 0; ct < 4; ++ct) { Oacc[ct][0]=0.f; Oacc[ct][1]=0.f; Oacc[ct][2]=0.f; Oacc[ct][3]=0.f; }

    for (int kk = 0; kk < 4; ++kk) {
        int kb = kbh*4 + kk;
        __syncthreads();                                   // prev PV reads done
        // ---- stage K (8 iters x 256 thr) ----
        const size_t kbase = (size_t)(h*8 + kb) * 256 * 64;
#pragma unroll
        for (int i = 0; i < 8; ++i) {
            int g = i*256 + t;
            int key = g >> 3, cc = g & 7;
            int tt = key >> 4, klo = key & 15, kc = cc >> 2, qs = cc & 3;
            U32x4 v = *(const U32x4*)&Kg[kbase + (size_t)key*64 + cc*8];
            *(U32x4*)&S[(size_t)(((tt*2 + kc)*64) + qs*16 + klo)*8] = v;
        }
        __syncthreads();

        // ---- QK^T ----
        f32x4 Sfr[16];
#pragma unroll
        for (int tt = 0; tt < 16; ++tt) { Sfr[tt][0]=0.f; Sfr[tt][1]=0.f; Sfr[tt][2]=0.f; Sfr[tt][3]=0.f; }
#pragma unroll
        for (int tt = 0; tt < 16; ++tt) {
            bf16x8 k0 = *(const bf16x8*)&S[(size_t)((tt*2 + 0)*64 + l)*8];
            bf16x8 k1 = *(const bf16x8*)&S[(size_t)((tt*2 + 1)*64 + l)*8];
            Sfr[tt] = __builtin_amdgcn_mfma_f32_16x16x32_bf16(qf0, k0, Sfr[tt], 0, 0, 0);
            Sfr[tt] = __builtin_amdgcn_mfma_f32_16x16x32_bf16(qf1, k1, Sfr[tt], 0, 0, 0);
        }

        // ---- exact softmax per q-row (per key-batch of 256 keys) ----
        float inv[4];
#pragma unroll
        for (int r = 0; r < 4; ++r) {
            float m = Sfr[0][r];
#pragma unroll
            for (int tt = 1; tt < 16; ++tt) m = fmaxf(m, Sfr[tt][r]);
#pragma unroll
            for (int off = 1; off < 16; off <<= 1) m = fmaxf(m, __shfl_xor(m, off));
            float s = 0.f;
#pragma unroll
            for (int tt = 0; tt < 16; ++tt) {
                float e = __expf(Sfr[tt][r] - m);
                Sfr[tt][r] = e; s += e;
            }
#pragma unroll
            for (int off = 1; off < 16; off <<= 1) s += __shfl_xor(s, off);
            inv[r] = 1.f / s;
        }
        __syncthreads();                                   // all K reads done

        // ---- P: C-layout -> LDS [key][q64], stride 66 u16 ----
#pragma unroll
        for (int tt = 0; tt < 16; ++tt)
#pragma unroll
            for (int r = 0; r < 4; ++r)
                S[(tt*16 + col)*66 + w*16 + quad*4 + r] = f2bf(Sfr[tt][r] * inv[r]);

        bf16x8 pf[8];
#pragma unroll
        for (int ch = 0; ch < 8; ++ch)
#pragma unroll
            for (int j = 0; j < 8; ++j)
                pf[ch][j] = (short)S[(ch*32 + quad*8 + j)*66 + w*16 + col];
        __syncthreads();                                   // all P reads done

        // ---- stage V (XOR-swizzled, 8 iters x 256 thr) ----
        const size_t vbase = (size_t)(h*8 + kb) * 64 * 256;
#pragma unroll
        for (int i = 0; i < 8; ++i) {
            int g = i*256 + t;
            int cg = g >> 5, k16 = g & 31;
            int ct = cg >> 4, clo = cg & 15, ch = k16 >> 2, qs = k16 & 3;
            U32x4 v = *(const U32x4*)&Vg[vbase + (size_t)cg*256 + k16*8];
            *(U32x4*)&S[(size_t)(((ch*4 + ct)*64) + ((qs*16 + clo) ^ ch))*8] = v;
        }
        __syncthreads();

        // ---- PV ----
#pragma unroll
        for (int ch = 0; ch < 8; ++ch)
#pragma unroll
            for (int ct = 0; ct < 4; ++ct) {
                bf16x8 vb = *(const bf16x8*)&S[(size_t)(((ch*4 + ct)*64) + (l ^ ch))*8];
                Oacc[ct] = __builtin_amdgcn_mfma_f32_16x16x32_bf16(pf[ch], vb, Oacc[ct], 0, 0, 0);
            }
    }

    // ---- write fp32 partial: Opart[kbh][h][b][n][c] ----
    float* Od = Opart + (size_t)kbh * 1048576;
    const size_t obase = (size_t)(h*8 + b) * 256 * 64;
    int n0 = ntq*64 + w*16 + quad*4;
#pragma unroll
    for (int ct = 0; ct < 4; ++ct)
#pragma unroll
        for (int r = 0; r < 4; ++r)
            Od[obase + (size_t)(n0 + r)*64 + ct*16 + col] = Oacc[ct][r];
}

// ---------------- K2b: scalar reducer — OpA += OpB (in place) ------------------
__global__ void k_osum(float* __restrict__ OpA, const float* __restrict__ OpB)
{
    size_t i = ((size_t)blockIdx.x * 256 + threadIdx.x) * 4;
    float4 a = *(const float4*)&OpA[i];
    float4 b = *(const float4*)&OpB[i];
    a.x += b.x; a.y += b.y; a.z += b.z; a.w += b.w;
    *(float4*)&OpA[i] = a;
}

// ---------------- K3: Wa projection + bias + residual (scalar, pipelined) ------
__global__ void k_proj_res(
    const float* __restrict__ Oph, const u16* __restrict__ Wa,
    const u16* __restrict__ ba, const u16* __restrict__ x1,
    float* __restrict__ Ap, const int* __restrict__ flag)
{
    const int f32 = *flag;
    int id = blockIdx.x;
    int tt = id >> 2;           // 0..63 (32-token tiles)
    int it = id & 3;            // i tile 0..3
    int tok0 = tt * 32;
    int b  = tok0 >> 8;
    int n0 = tok0 & 255;

    __shared__ float Was[64][68];  // Was[o][i]
    __shared__ float Os[64][36];   // Os[o][tok32]

    int t = threadIdx.x;
    int lane64 = t & 63, quad = t >> 6;
    int ig = t & 15;
    int tg = t >> 4;

    int tk = t & 31;
    int hh = t >> 5;

    float wreg[16];
    float oreg[8];

    {
#pragma unroll
        for (int p = 0; p < 16; ++p) {
            int i = quad + 4*p;
            wreg[p] = ld(Wa, (size_t)(it*64 + i)*EMB + 0*64 + lane64, f32);
        }
        const float* src = &Oph[(((size_t)(hh*8 + b))*256 + n0 + tk)*64 + 0*8];
        float4 v0 = *(const float4*)&src[0];
        float4 v1 = *(const float4*)&src[4];
        oreg[0]=v0.x; oreg[1]=v0.y; oreg[2]=v0.z; oreg[3]=v0.w;
        oreg[4]=v1.x; oreg[5]=v1.y; oreg[6]=v1.z; oreg[7]=v1.w;
    }

    float acc[8];
#pragma unroll
    for (int j = 0; j < 8; ++j) acc[j] = 0.f;

    for (int kc = 0; kc < 8; ++kc) {
        __syncthreads();
#pragma unroll
        for (int p = 0; p < 16; ++p)
            Was[lane64][quad + 4*p] = wreg[p];
#pragma unroll
        for (int e = 0; e < 8; ++e)
            Os[e*8 + hh][tk] = oreg[e];
        __syncthreads();

        if (kc < 7) {
            int kn = kc + 1;
#pragma unroll
            for (int p = 0; p < 16; ++p) {
                int i = quad + 4*p;
                wreg[p] = ld(Wa, (size_t)(it*64 + i)*EMB + kn*64 + lane64, f32);
            }
            const float* src = &Oph[(((size_t)(hh*8 + b))*256 + n0 + tk)*64 + kn*8];
            float4 v0 = *(const float4*)&src[0];
            float4 v1 = *(const float4*)&src[4];
            oreg[0]=v0.x; oreg[1]=v0.y; oreg[2]=v0.z; oreg[3]=v0.w;
            oreg[4]=v1.x; oreg[5]=v1.y; oreg[6]=v1.z; oreg[7]=v1.w;
        }

#pragma unroll 8
        for (int o = 0; o < 64; ++o) {
            float4 w4 = *(const float4*)&Was[o][ig*4];
            float2 t2 = *(const float2*)&Os[o][tg*2];
            acc[0] += w4.x*t2.x; acc[1] += w4.y*t2.x;
            acc[2] += w4.z*t2.x; acc[3] += w4.w*t2.x;
            acc[4] += w4.x*t2.y; acc[5] += w4.y*t2.y;
            acc[6] += w4.z*t2.y; acc[7] += w4.w*t2.y;
        }
    }

    int i0 = it*64 + ig*4;
    float ba0 = ld(ba, i0+0, f32), ba1 = ld(ba, i0+1, f32);
    float ba2 = ld(ba, i0+2, f32), ba3 = ld(ba, i0+3, f32);
#pragma unroll
    for (int jt = 0; jt < 2; ++jt) {
        int token = tok0 + tg*2 + jt;
        int n = n0 + tg*2 + jt;
        float4 v;
        v.x = acc[jt*4+0] + ba0 + ld(x1, ((size_t)b*CIN + i0+0)*NT + n, f32);
        v.y = acc[jt*4+1] + ba1 + ld(x1, ((size_t)b*CIN + i0+1)*NT + n, f32);
        v.z = acc[jt*4+2] + ba2 + ld(x1, ((size_t)b*CIN + i0+2)*NT + n, f32);
        v.w = acc[jt*4+3] + ba3 + ld(x1, ((size_t)b*CIN + i0+3)*NT + n, f32);
        *(float4*)&Ap[(size_t)token*CIN + i0] = v;
    }
}

// ---------------- K4: LayerNorm + Linear + ReLU -> out ----------------
__global__ void k_ln_out(
    const float* __restrict__ Ap, const u16* __restrict__ ln_g,
    const u16* __restrict__ ln_b, const u16* __restrict__ Wl,
    const u16* __restrict__ bl, u16* __restrict__ out,
    const int* __restrict__ flag)
{
    const int f32 = *flag;
    int tok0 = blockIdx.x * 16;
    int b  = tok0 >> 8;
    int n0 = tok0 & 255;

    __shared__ float At[16][260];

    int t = threadIdx.x;
#pragma unroll
    for (int k = 0; k < 16; ++k)
        At[k][t] = Ap[((size_t)tok0 + k)*CIN + t];
    __syncthreads();

    {
        int kk = t >> 4, lme = t & 15;
        float s = 0.f, s2 = 0.f;
#pragma unroll
        for (int ii = 0; ii < 16; ++ii) { float v = At[kk][lme + 16*ii]; s += v; s2 += v*v; }
#pragma unroll
        for (int off = 1; off < 16; off <<= 1) { s += __shfl_xor(s, off); s2 += __shfl_xor(s2, off); }
        float mu   = s  * (1.f/256.f);
        float var  = s2 * (1.f/256.f) - mu*mu;
        float rstd = rsqrtf(var + 1e-5f);
#pragma unroll
        for (int ii = 0; ii < 16; ++ii) {
            int i = lme + 16*ii;
            float v = At[kk][i];
            At[kk][i] = (v - mu) * rstd * ld(ln_g, i, f32) + ld(ln_b, i, f32);
        }
    }
    __syncthreads();

    int j = t;
    float acc[16];
#pragma unroll
    for (int k = 0; k < 16; ++k) acc[k] = 0.f;

    if (f32) {
        const float* wrow = (const float*)Wl + (size_t)j*CIN;
#pragma unroll 2
        for (int i4 = 0; i4 < 64; ++i4) {
            float4 w4 = *(const float4*)&wrow[4*i4];
#pragma unroll
            for (int k = 0; k < 16; ++k) {
                float4 a = *(const float4*)&At[k][4*i4];
                acc[k] += w4.x*a.x + w4.y*a.y + w4.z*a.z + w4.w*a.w;
            }
        }
    } else {
        const u32* wrow = (const u32*)(Wl + (size_t)j*CIN);
#pragma unroll 2
        for (int i4 = 0; i4 < 64; ++i4) {
            u32 w01 = wrow[2*i4+0], w23 = wrow[2*i4+1];
            float c0 = bf2f((u16)(w01 & 0xFFFFu)), c1 = bf2f((u16)(w01 >> 16));
            float c2 = bf2f((u16)(w23 & 0xFFFFu)), c3 = bf2f((u16)(w23 >> 16));
#pragma unroll
            for (int k = 0; k < 16; ++k) {
                float4 a = *(const float4*)&At[k][4*i4];
                acc[k] += c0*a.x + c1*a.y + c2*a.z + c3*a.w;
            }
        }
    }

    float blv = ld(bl, j, f32);
    size_t obase = ((size_t)b*CIN + j)*NT + n0;
    if (f32) {
        float* o32 = (float*)out;
#pragma unroll
        for (int k = 0; k < 16; ++k)
            o32[obase + k] = fmaxf(acc[k] + blv, 0.f);
    } else {
        u32 pk[8];
#pragma unroll
        for (int k = 0; k < 8; ++k) {
            float f0 = fmaxf(acc[2*k+0] + blv, 0.f);
            float f1 = fmaxf(acc[2*k+1] + blv, 0.f);
            pk[k] = (u32)f2bf(f0) | ((u32)f2bf(f1) << 16);
        }
        U32x4* dst = (U32x4*)(out + obase);
        U32x4 a0; a0.x = pk[0]; a0.y = pk[1]; a0.z = pk[2]; a0.w = pk[3];
        U32x4 a1; a1.x = pk[4]; a1.y = pk[5]; a1.z = pk[6]; a1.w = pk[7];
        dst[0] = a0;
        dst[1] = a1;
    }
}

// ---------------------------------------------------------------
// Workspace: 16,777,280 B — byte-identical footprint to the proven-green R3.
//   flag 64B | Qg 2MB | Kg 2MB | Vg 2MB | OpA 4MB | OpB 4MB | Ap 2MB
extern "C" void kernel_launch(void* const* d_in, const int* in_sizes, int n_in,
                              void* d_out, int out_size, void* d_ws, size_t ws_size,
                              hipStream_t stream)
{
    const u16* x1   = (const u16*)d_in[0];
    const u16* x2   = (const u16*)d_in[1];
    const u16* Wq   = (const u16*)d_in[2];
    const u16* bq   = (const u16*)d_in[3];
    const u16* Wk   = (const u16*)d_in[4];
    const u16* bk   = (const u16*)d_in[5];
    const u16* Wv   = (const u16*)d_in[6];
    const u16* bv   = (const u16*)d_in[7];
    const u16* Wa   = (const u16*)d_in[8];
    const u16* ba   = (const u16*)d_in[9];
    const u16* ln_g = (const u16*)d_in[10];
    const u16* ln_b = (const u16*)d_in[11];
    const u16* Wl   = (const u16*)d_in[12];
    const u16* bl   = (const u16*)d_in[13];
    u16* out = (u16*)d_out;

    int* flag = (int*)d_ws;
    u16* Qg = (u16*)d_ws + 32;                    // +64 B
    u16* Kg = Qg + (size_t)BB*EMB*NT;             // 1M u16 each
    u16* Vg = Kg + (size_t)BB*EMB*NT;
    float* OpA = (float*)(Vg + (size_t)BB*EMB*NT);   // 1M f32 (partial kbh=0 / final O)
    float* OpB = OpA + 1048576;                      // 1M f32 (partial kbh=1)
    float* Ap  = OpB + 1048576;                      // 512K f32

    k_detect  <<<1,    256, 0, stream>>>(x1, flag);
    k_qkv     <<<768,  256, 0, stream>>>(x1, x2, Wq, bq, Wk, bk, Wv, bv, Qg, Kg, Vg, flag);
    k_attn    <<<512,  256, 0, stream>>>(Qg, Kg, Vg, OpA);
    k_osum    <<<1024, 256, 0, stream>>>(OpA, OpB);
    k_proj_res<<<256,  256, 0, stream>>>(OpA, Wa, ba, x1, Ap, flag);
    k_ln_out  <<<128,  256, 0, stream>>>(Ap, ln_g, ln_b, Wl, bl, out, flag);
}

// Round 16
// 211.784 us; speedup vs baseline: 1.0968x; 1.0968x over previous
//
#include <hip/hip_runtime.h>

typedef unsigned short u16;
typedef unsigned int   u32;
typedef __attribute__((ext_vector_type(8))) short bf16x8;
typedef __attribute__((ext_vector_type(4))) float f32x4;

#define BB   8
#define CIN  256
#define NT   256
#define EMB  512
#define NH   8

// ---- bf16 <-> f32 via raw bits ----
__device__ __forceinline__ float bf2f(u16 b) {
    union { u32 u; float f; } v; v.u = ((u32)b) << 16; return v.f;
}
__device__ __forceinline__ u16 f2bf(float f) {
    union { float f; u32 u; } v; v.f = f;
    u32 r = v.u + 0x7FFFu + ((v.u >> 16) & 1u);  // RNE
    return (u16)(r >> 16);
}
__device__ __forceinline__ float ld(const u16* base, size_t idx, int f32) {
    return f32 ? ((const float*)base)[idx] : bf2f(base[idx]);
}

struct alignas(16) U32x4 { u32 x, y, z, w; };

// acc[r*S + c] += a4[r] * b4[c]
#define FMA44(AP, S, A4, B4) do { \
  (AP)[0*(S)+0] += (A4).x*(B4).x; (AP)[0*(S)+1] += (A4).x*(B4).y; (AP)[0*(S)+2] += (A4).x*(B4).z; (AP)[0*(S)+3] += (A4).x*(B4).w; \
  (AP)[1*(S)+0] += (A4).y*(B4).x; (AP)[1*(S)+1] += (A4).y*(B4).y; (AP)[1*(S)+2] += (A4).y*(B4).z; (AP)[1*(S)+3] += (A4).y*(B4).w; \
  (AP)[2*(S)+0] += (A4).z*(B4).x; (AP)[2*(S)+1] += (A4).z*(B4).y; (AP)[2*(S)+2] += (A4).z*(B4).z; (AP)[2*(S)+3] += (A4).z*(B4).w; \
  (AP)[3*(S)+0] += (A4).w*(B4).x; (AP)[3*(S)+1] += (A4).w*(B4).y; (AP)[3*(S)+2] += (A4).w*(B4).z; (AP)[3*(S)+3] += (A4).w*(B4).w; \
} while (0)

// ---------------- K0: dtype detector (flag=1 means fp32 inputs) ----------------
__global__ void k_detect(const u16* __restrict__ x1, int* __restrict__ flag) {
    __shared__ int cnt;
    if (threadIdx.x == 0) cnt = 0;
    __syncthreads();
    int t = threadIdx.x;
    int local = 0;
    for (int j = t * 16; j < t * 16 + 16; j += 2) {
        u16 w = x1[j];
        int e = (w >> 7) & 0xFF;
        if (e >= 100 && e <= 145) local++;
    }
    atomicAdd(&cnt, local);
    __syncthreads();
    if (t == 0) *flag = (cnt >= 1200) ? 0 : 1;
}

// ---------------- K1: QKV projections (scalar, pipelined) ----------------------
// Q,K: [h][b][n][c64] (c contig);  V: [h][b][c64][n] (n contig)
__global__ void k_qkv(
    const u16* __restrict__ x1, const u16* __restrict__ x2,
    const u16* __restrict__ Wq, const u16* __restrict__ bq,
    const u16* __restrict__ Wk, const u16* __restrict__ bk,
    const u16* __restrict__ Wv, const u16* __restrict__ bv,
    u16* __restrict__ Qg, u16* __restrict__ Kg, u16* __restrict__ Vg,
    const int* __restrict__ flag)
{
    const int f32 = *flag;
    int id = blockIdx.x;
    int proj = id >> 8;            // 0=q,1=k,2=v
    int rem  = id & 255;
    int b  = rem >> 5;
    int ot = (rem >> 2) & 7;       // o-tile (64 outputs = 8 c x 8 h)
    int nt = rem & 3;              // n-tile (64 tokens)

    const u16* X    = (proj == 0) ? x1 : x2;
    const u16* W    = (proj == 0) ? Wq : (proj == 1) ? Wk : Wv;
    const u16* bias = (proj == 0) ? bq : (proj == 1) ? bk : bv;

    __shared__ float Ws[64][68];   // stage: Ws[i][o]; epilogue: Ls[o_local][n_local]
    __shared__ float Xs[64][64];   // Xs[i][n]

    int t = threadIdx.x;
    int lane64 = t & 63;
    int quad   = t >> 6;
    int og = t >> 4;
    int ng = t & 15;

    float acc[16];
#pragma unroll
    for (int j = 0; j < 16; ++j) acc[j] = 0.f;

    float wreg[16], xreg[16];
#pragma unroll
    for (int p = 0; p < 16; ++p) {
        int o = quad + 4*p;
        wreg[p] = ld(W, (size_t)(ot*64 + o)*CIN + 0*64 + lane64, f32);
    }
#pragma unroll
    for (int p = 0; p < 16; ++p) {
        int i = quad + 4*p;
        xreg[p] = ld(X, ((size_t)b*CIN + 0*64 + i)*NT + nt*64 + lane64, f32);
    }

    for (int kc = 0; kc < 4; ++kc) {
        __syncthreads();
#pragma unroll
        for (int p = 0; p < 16; ++p)
            Ws[lane64][quad + 4*p] = wreg[p];
#pragma unroll
        for (int p = 0; p < 16; ++p)
            Xs[quad + 4*p][lane64] = xreg[p];
        __syncthreads();

        if (kc < 3) {
            int kn = kc + 1;
#pragma unroll
            for (int p = 0; p < 16; ++p) {
                int o = quad + 4*p;
                wreg[p] = ld(W, (size_t)(ot*64 + o)*CIN + kn*64 + lane64, f32);
            }
#pragma unroll
            for (int p = 0; p < 16; ++p) {
                int i = quad + 4*p;
                xreg[p] = ld(X, ((size_t)b*CIN + kn*64 + i)*NT + nt*64 + lane64, f32);
            }
        }

#pragma unroll 8
        for (int i = 0; i < 64; ++i) {
            float4 w4 = *(const float4*)&Ws[i][og*4];
            float4 x4 = *(const float4*)&Xs[i][ng*4];
            FMA44(acc, 4, w4, x4);
        }
    }
    __syncthreads();

    // ---- epilogue ----
#pragma unroll
    for (int jo = 0; jo < 4; ++jo) {
        int o = ot*64 + og*4 + jo;
        float bb = ld(bias, o, f32);
#pragma unroll
        for (int jn = 0; jn < 4; ++jn)
            Ws[og*4 + jo][ng*4 + jn] = acc[jo*4 + jn] + bb;
    }
    __syncthreads();

    if (proj < 2) {
        u16* OUT = (proj == 0) ? Qg : Kg;
        int hh = t >> 5;
        int nb = t & 31;
#pragma unroll
        for (int p = 0; p < 2; ++p) {
            int nn = nb + 32*p;
            u32 pk[4];
#pragma unroll
            for (int e = 0; e < 4; ++e) {
                u16 lo = f2bf(Ws[(2*e  )*8 + hh][nn]);
                u16 hi = f2bf(Ws[(2*e+1)*8 + hh][nn]);
                pk[e] = (u32)lo | ((u32)hi << 16);
            }
            U32x4 v; v.x = pk[0]; v.y = pk[1]; v.z = pk[2]; v.w = pk[3];
            *(U32x4*)&OUT[((size_t)((hh*8 + b)*256) + nt*64 + nn)*64 + ot*8] = v;
        }
    } else {
        int rr = t >> 2;
        int hh = rr & 7, cl = rr >> 3;
        int nq = t & 3;
        u32 pk[8];
#pragma unroll
        for (int e = 0; e < 8; ++e) {
            u16 lo = f2bf(Ws[cl*8 + hh][nq*16 + 2*e  ]);
            u16 hi = f2bf(Ws[cl*8 + hh][nq*16 + 2*e+1]);
            pk[e] = (u32)lo | ((u32)hi << 16);
        }
        size_t base = ((size_t)((hh*8 + b)*64) + ot*8 + cl)*256 + nt*64 + nq*16;
        U32x4 v0; v0.x = pk[0]; v0.y = pk[1]; v0.z = pk[2]; v0.w = pk[3];
        U32x4 v1; v1.x = pk[4]; v1.y = pk[5]; v1.z = pk[6]; v1.w = pk[7];
        *(U32x4*)&Vg[base]     = v0;
        *(U32x4*)&Vg[base + 8] = v1;
    }
}

// ---------------- K2: cross-batch attention, MFMA 16x16x32 bf16 ----------------
// R14 green body (kb-split reverted: co-residency didn't pay, k_osum overhead
// did). 256 thr / 64 q per block, grid 256 = h(8) x b(8) x ntq(4).
__global__ __launch_bounds__(256) void k_attn(
    const u16* __restrict__ Qg, const u16* __restrict__ Kg,
    const u16* __restrict__ Vg, float* __restrict__ Oph)
{
    int bid = blockIdx.x;
    int h   = bid >> 5;
    int b   = (bid >> 2) & 7;
    int ntq = bid & 3;

    int t = threadIdx.x;
    int l = t & 63, w = t >> 6;
    int quad = l >> 4, col = l & 15;

    __shared__ __align__(16) u16 S[16896];   // 33 KB, phases: K | P(stride 66) | V

    int q = ntq*64 + w*16 + col;
    const size_t qrow = ((size_t)(h*8 + b)*256 + q)*64;
    bf16x8 qf0 = *(const bf16x8*)&Qg[qrow +  0 + quad*8];
    bf16x8 qf1 = *(const bf16x8*)&Qg[qrow + 32 + quad*8];

    f32x4 Oacc[4];
#pragma unroll
    for (int ct = 0; ct < 4; ++ct) { Oacc[ct][0]=0.f; Oacc[ct][1]=0.f; Oacc[ct][2]=0.f; Oacc[ct][3]=0.f; }

    for (int kb = 0; kb < 8; ++kb) {
        __syncthreads();                                   // prev PV reads done
        // ---- stage K (8 iters x 256 thr) ----
        const size_t kbase = (size_t)(h*8 + kb) * 256 * 64;
#pragma unroll
        for (int i = 0; i < 8; ++i) {
            int g = i*256 + t;
            int key = g >> 3, cc = g & 7;
            int tt = key >> 4, klo = key & 15, kc = cc >> 2, qs = cc & 3;
            U32x4 v = *(const U32x4*)&Kg[kbase + (size_t)key*64 + cc*8];
            *(U32x4*)&S[(size_t)(((tt*2 + kc)*64) + qs*16 + klo)*8] = v;
        }
        __syncthreads();

        // ---- QK^T ----
        f32x4 Sfr[16];
#pragma unroll
        for (int tt = 0; tt < 16; ++tt) { Sfr[tt][0]=0.f; Sfr[tt][1]=0.f; Sfr[tt][2]=0.f; Sfr[tt][3]=0.f; }
#pragma unroll
        for (int tt = 0; tt < 16; ++tt) {
            bf16x8 k0 = *(const bf16x8*)&S[(size_t)((tt*2 + 0)*64 + l)*8];
            bf16x8 k1 = *(const bf16x8*)&S[(size_t)((tt*2 + 1)*64 + l)*8];
            Sfr[tt] = __builtin_amdgcn_mfma_f32_16x16x32_bf16(qf0, k0, Sfr[tt], 0, 0, 0);
            Sfr[tt] = __builtin_amdgcn_mfma_f32_16x16x32_bf16(qf1, k1, Sfr[tt], 0, 0, 0);
        }

        // ---- exact softmax per q-row ----
        float inv[4];
#pragma unroll
        for (int r = 0; r < 4; ++r) {
            float m = Sfr[0][r];
#pragma unroll
            for (int tt = 1; tt < 16; ++tt) m = fmaxf(m, Sfr[tt][r]);
#pragma unroll
            for (int off = 1; off < 16; off <<= 1) m = fmaxf(m, __shfl_xor(m, off));
            float s = 0.f;
#pragma unroll
            for (int tt = 0; tt < 16; ++tt) {
                float e = __expf(Sfr[tt][r] - m);
                Sfr[tt][r] = e; s += e;
            }
#pragma unroll
            for (int off = 1; off < 16; off <<= 1) s += __shfl_xor(s, off);
            inv[r] = 1.f / s;
        }
        __syncthreads();                                   // all K reads done

        // ---- P: C-layout -> LDS [key][q64], stride 66 u16 ----
#pragma unroll
        for (int tt = 0; tt < 16; ++tt)
#pragma unroll
            for (int r = 0; r < 4; ++r)
                S[(tt*16 + col)*66 + w*16 + quad*4 + r] = f2bf(Sfr[tt][r] * inv[r]);

        bf16x8 pf[8];
#pragma unroll
        for (int ch = 0; ch < 8; ++ch)
#pragma unroll
            for (int j = 0; j < 8; ++j)
                pf[ch][j] = (short)S[(ch*32 + quad*8 + j)*66 + w*16 + col];
        __syncthreads();                                   // all P reads done

        // ---- stage V (XOR-swizzled, 8 iters x 256 thr) ----
        const size_t vbase = (size_t)(h*8 + kb) * 64 * 256;
#pragma unroll
        for (int i = 0; i < 8; ++i) {
            int g = i*256 + t;
            int cg = g >> 5, k16 = g & 31;
            int ct = cg >> 4, clo = cg & 15, ch = k16 >> 2, qs = k16 & 3;
            U32x4 v = *(const U32x4*)&Vg[vbase + (size_t)cg*256 + k16*8];
            *(U32x4*)&S[(size_t)(((ch*4 + ct)*64) + ((qs*16 + clo) ^ ch))*8] = v;
        }
        __syncthreads();

        // ---- PV ----
#pragma unroll
        for (int ch = 0; ch < 8; ++ch)
#pragma unroll
            for (int ct = 0; ct < 4; ++ct) {
                bf16x8 vb = *(const bf16x8*)&S[(size_t)(((ch*4 + ct)*64) + (l ^ ch))*8];
                Oacc[ct] = __builtin_amdgcn_mfma_f32_16x16x32_bf16(pf[ch], vb, Oacc[ct], 0, 0, 0);
            }
    }

    // ---- write O: Oph[h][b][n][c] fp32 ----
    const size_t obase = (size_t)(h*8 + b) * 256 * 64;
    int n0 = ntq*64 + w*16 + quad*4;
#pragma unroll
    for (int ct = 0; ct < 4; ++ct)
#pragma unroll
        for (int r = 0; r < 4; ++r)
            Oph[obase + (size_t)(n0 + r)*64 + ct*16 + col] = Oacc[ct][r];
}

// ---------------- K3: Wa projection + bias + residual (scalar, pipelined) ------
__global__ void k_proj_res(
    const float* __restrict__ Oph, const u16* __restrict__ Wa,
    const u16* __restrict__ ba, const u16* __restrict__ x1,
    float* __restrict__ Ap, const int* __restrict__ flag)
{
    const int f32 = *flag;
    int id = blockIdx.x;
    int tt = id >> 2;           // 0..63 (32-token tiles)
    int it = id & 3;            // i tile 0..3
    int tok0 = tt * 32;
    int b  = tok0 >> 8;
    int n0 = tok0 & 255;

    __shared__ float Was[64][68];  // Was[o][i]
    __shared__ float Os[64][36];   // Os[o][tok32]

    int t = threadIdx.x;
    int lane64 = t & 63, quad = t >> 6;
    int ig = t & 15;
    int tg = t >> 4;

    int tk = t & 31;
    int hh = t >> 5;

    float wreg[16];
    float oreg[8];

    {
#pragma unroll
        for (int p = 0; p < 16; ++p) {
            int i = quad + 4*p;
            wreg[p] = ld(Wa, (size_t)(it*64 + i)*EMB + 0*64 + lane64, f32);
        }
        const float* src = &Oph[(((size_t)(hh*8 + b))*256 + n0 + tk)*64 + 0*8];
        float4 v0 = *(const float4*)&src[0];
        float4 v1 = *(const float4*)&src[4];
        oreg[0]=v0.x; oreg[1]=v0.y; oreg[2]=v0.z; oreg[3]=v0.w;
        oreg[4]=v1.x; oreg[5]=v1.y; oreg[6]=v1.z; oreg[7]=v1.w;
    }

    float acc[8];
#pragma unroll
    for (int j = 0; j < 8; ++j) acc[j] = 0.f;

    for (int kc = 0; kc < 8; ++kc) {
        __syncthreads();
#pragma unroll
        for (int p = 0; p < 16; ++p)
            Was[lane64][quad + 4*p] = wreg[p];
#pragma unroll
        for (int e = 0; e < 8; ++e)
            Os[e*8 + hh][tk] = oreg[e];
        __syncthreads();

        if (kc < 7) {
            int kn = kc + 1;
#pragma unroll
            for (int p = 0; p < 16; ++p) {
                int i = quad + 4*p;
                wreg[p] = ld(Wa, (size_t)(it*64 + i)*EMB + kn*64 + lane64, f32);
            }
            const float* src = &Oph[(((size_t)(hh*8 + b))*256 + n0 + tk)*64 + kn*8];
            float4 v0 = *(const float4*)&src[0];
            float4 v1 = *(const float4*)&src[4];
            oreg[0]=v0.x; oreg[1]=v0.y; oreg[2]=v0.z; oreg[3]=v0.w;
            oreg[4]=v1.x; oreg[5]=v1.y; oreg[6]=v1.z; oreg[7]=v1.w;
        }

#pragma unroll 8
        for (int o = 0; o < 64; ++o) {
            float4 w4 = *(const float4*)&Was[o][ig*4];
            float2 t2 = *(const float2*)&Os[o][tg*2];
            acc[0] += w4.x*t2.x; acc[1] += w4.y*t2.x;
            acc[2] += w4.z*t2.x; acc[3] += w4.w*t2.x;
            acc[4] += w4.x*t2.y; acc[5] += w4.y*t2.y;
            acc[6] += w4.z*t2.y; acc[7] += w4.w*t2.y;
        }
    }

    int i0 = it*64 + ig*4;
    float ba0 = ld(ba, i0+0, f32), ba1 = ld(ba, i0+1, f32);
    float ba2 = ld(ba, i0+2, f32), ba3 = ld(ba, i0+3, f32);
#pragma unroll
    for (int jt = 0; jt < 2; ++jt) {
        int token = tok0 + tg*2 + jt;
        int n = n0 + tg*2 + jt;
        float4 v;
        v.x = acc[jt*4+0] + ba0 + ld(x1, ((size_t)b*CIN + i0+0)*NT + n, f32);
        v.y = acc[jt*4+1] + ba1 + ld(x1, ((size_t)b*CIN + i0+1)*NT + n, f32);
        v.z = acc[jt*4+2] + ba2 + ld(x1, ((size_t)b*CIN + i0+2)*NT + n, f32);
        v.w = acc[jt*4+3] + ba3 + ld(x1, ((size_t)b*CIN + i0+3)*NT + n, f32);
        *(float4*)&Ap[(size_t)token*CIN + i0] = v;
    }
}

// ---------------- K4: LayerNorm + Linear + ReLU -> out -------------------------
// ONLY kernel changed this round: tokens/block 16 -> 8, grid 128 -> 256
// (was the last 0.5-blocks/CU kernel). LN reduction now 32 lanes x 8 values
// (intra-wave shuffles), GEMM acc[16] -> acc[8], store one U32x4 per thread.
__global__ void k_ln_out(
    const float* __restrict__ Ap, const u16* __restrict__ ln_g,
    const u16* __restrict__ ln_b, const u16* __restrict__ Wl,
    const u16* __restrict__ bl, u16* __restrict__ out,
    const int* __restrict__ flag)
{
    const int f32 = *flag;
    int tok0 = blockIdx.x * 8;
    int b  = tok0 >> 8;
    int n0 = tok0 & 255;

    __shared__ float At[8][260];

    int t = threadIdx.x;
#pragma unroll
    for (int k = 0; k < 8; ++k)
        At[k][t] = Ap[((size_t)tok0 + k)*CIN + t];
    __syncthreads();

    {   // LN: 32 lanes per token, 8 i-values each
        int kk = t >> 5, lme = t & 31;
        float s = 0.f, s2 = 0.f;
#pragma unroll
        for (int ii = 0; ii < 8; ++ii) { float v = At[kk][lme + 32*ii]; s += v; s2 += v*v; }
#pragma unroll
        for (int off = 1; off < 32; off <<= 1) { s += __shfl_xor(s, off); s2 += __shfl_xor(s2, off); }
        float mu   = s  * (1.f/256.f);
        float var  = s2 * (1.f/256.f) - mu*mu;
        float rstd = rsqrtf(var + 1e-5f);
#pragma unroll
        for (int ii = 0; ii < 8; ++ii) {
            int i = lme + 32*ii;
            float v = At[kk][i];
            At[kk][i] = (v - mu) * rstd * ld(ln_g, i, f32) + ld(ln_b, i, f32);
        }
    }
    __syncthreads();

    int j = t;
    float acc[8];
#pragma unroll
    for (int k = 0; k < 8; ++k) acc[k] = 0.f;

    if (f32) {
        const float* wrow = (const float*)Wl + (size_t)j*CIN;
#pragma unroll 2
        for (int i4 = 0; i4 < 64; ++i4) {
            float4 w4 = *(const float4*)&wrow[4*i4];
#pragma unroll
            for (int k = 0; k < 8; ++k) {
                float4 a = *(const float4*)&At[k][4*i4];
                acc[k] += w4.x*a.x + w4.y*a.y + w4.z*a.z + w4.w*a.w;
            }
        }
    } else {
        const u32* wrow = (const u32*)(Wl + (size_t)j*CIN);
#pragma unroll 2
        for (int i4 = 0; i4 < 64; ++i4) {
            u32 w01 = wrow[2*i4+0], w23 = wrow[2*i4+1];
            float c0 = bf2f((u16)(w01 & 0xFFFFu)), c1 = bf2f((u16)(w01 >> 16));
            float c2 = bf2f((u16)(w23 & 0xFFFFu)), c3 = bf2f((u16)(w23 >> 16));
#pragma unroll
            for (int k = 0; k < 8; ++k) {
                float4 a = *(const float4*)&At[k][4*i4];
                acc[k] += c0*a.x + c1*a.y + c2*a.z + c3*a.w;
            }
        }
    }

    float blv = ld(bl, j, f32);
    size_t obase = ((size_t)b*CIN + j)*NT + n0;
    if (f32) {
        float* o32 = (float*)out;
#pragma unroll
        for (int k = 0; k < 8; ++k)
            o32[obase + k] = fmaxf(acc[k] + blv, 0.f);
    } else {
        u32 pk[4];
#pragma unroll
        for (int k = 0; k < 4; ++k) {
            float f0 = fmaxf(acc[2*k+0] + blv, 0.f);
            float f1 = fmaxf(acc[2*k+1] + blv, 0.f);
            pk[k] = (u32)f2bf(f0) | ((u32)f2bf(f1) << 16);
        }
        U32x4 a0; a0.x = pk[0]; a0.y = pk[1]; a0.z = pk[2]; a0.w = pk[3];
        *(U32x4*)(out + obase) = a0;
    }
}

// ---------------------------------------------------------------
extern "C" void kernel_launch(void* const* d_in, const int* in_sizes, int n_in,
                              void* d_out, int out_size, void* d_ws, size_t ws_size,
                              hipStream_t stream)
{
    const u16* x1   = (const u16*)d_in[0];
    const u16* x2   = (const u16*)d_in[1];
    const u16* Wq   = (const u16*)d_in[2];
    const u16* bq   = (const u16*)d_in[3];
    const u16* Wk   = (const u16*)d_in[4];
    const u16* bk   = (const u16*)d_in[5];
    const u16* Wv   = (const u16*)d_in[6];
    const u16* bv   = (const u16*)d_in[7];
    const u16* Wa   = (const u16*)d_in[8];
    const u16* ba   = (const u16*)d_in[9];
    const u16* ln_g = (const u16*)d_in[10];
    const u16* ln_b = (const u16*)d_in[11];
    const u16* Wl   = (const u16*)d_in[12];
    const u16* bl   = (const u16*)d_in[13];
    u16* out = (u16*)d_out;

    int* flag = (int*)d_ws;
    u16* Qg = (u16*)d_ws + 32;                    // +64 B
    u16* Kg = Qg + (size_t)BB*EMB*NT;             // 1M u16 each
    u16* Vg = Kg + (size_t)BB*EMB*NT;
    float* Oph = (float*)(Vg + (size_t)BB*EMB*NT);
    float* Ap  = Oph + (size_t)BB*EMB*NT;

    k_detect  <<<1,   256, 0, stream>>>(x1, flag);
    k_qkv     <<<768, 256, 0, stream>>>(x1, x2, Wq, bq, Wk, bk, Wv, bv, Qg, Kg, Vg, flag);
    k_attn    <<<256, 256, 0, stream>>>(Qg, Kg, Vg, Oph);
    k_proj_res<<<256, 256, 0, stream>>>(Oph, Wa, ba, x1, Ap, flag);
    k_ln_out  <<<256, 256, 0, stream>>>(Ap, ln_g, ln_b, Wl, bl, out, flag);
}

// Round 17
// 207.205 us; speedup vs baseline: 1.1210x; 1.0221x over previous
//
#include <hip/hip_runtime.h>

typedef unsigned short u16;
typedef unsigned int   u32;
typedef __attribute__((ext_vector_type(8))) short bf16x8;
typedef __attribute__((ext_vector_type(4))) float f32x4;

#define BB   8
#define CIN  256
#define NT   256
#define EMB  512
#define NH   8

// ---- bf16 <-> f32 via raw bits ----
__device__ __forceinline__ float bf2f(u16 b) {
    union { u32 u; float f; } v; v.u = ((u32)b) << 16; return v.f;
}
__device__ __forceinline__ u16 f2bf(float f) {
    union { float f; u32 u; } v; v.f = f;
    u32 r = v.u + 0x7FFFu + ((v.u >> 16) & 1u);  // RNE
    return (u16)(r >> 16);
}
__device__ __forceinline__ float ld(const u16* base, size_t idx, int f32) {
    return f32 ? ((const float*)base)[idx] : bf2f(base[idx]);
}

struct alignas(16) U32x4 { u32 x, y, z, w; };

// acc[r*S + c] += a4[r] * b4[c]
#define FMA44(AP, S, A4, B4) do { \
  (AP)[0*(S)+0] += (A4).x*(B4).x; (AP)[0*(S)+1] += (A4).x*(B4).y; (AP)[0*(S)+2] += (A4).x*(B4).z; (AP)[0*(S)+3] += (A4).x*(B4).w; \
  (AP)[1*(S)+0] += (A4).y*(B4).x; (AP)[1*(S)+1] += (A4).y*(B4).y; (AP)[1*(S)+2] += (A4).y*(B4).z; (AP)[1*(S)+3] += (A4).y*(B4).w; \
  (AP)[2*(S)+0] += (A4).z*(B4).x; (AP)[2*(S)+1] += (A4).z*(B4).y; (AP)[2*(S)+2] += (A4).z*(B4).z; (AP)[2*(S)+3] += (A4).z*(B4).w; \
  (AP)[3*(S)+0] += (A4).w*(B4).x; (AP)[3*(S)+1] += (A4).w*(B4).y; (AP)[3*(S)+2] += (A4).w*(B4).z; (AP)[3*(S)+3] += (A4).w*(B4).w; \
} while (0)

// ---------------- K0: dtype detector (flag=1 means fp32 inputs) ----------------
__global__ void k_detect(const u16* __restrict__ x1, int* __restrict__ flag) {
    __shared__ int cnt;
    if (threadIdx.x == 0) cnt = 0;
    __syncthreads();
    int t = threadIdx.x;
    int local = 0;
    for (int j = t * 16; j < t * 16 + 16; j += 2) {
        u16 w = x1[j];
        int e = (w >> 7) & 0xFF;
        if (e >= 100 && e <= 145) local++;
    }
    atomicAdd(&cnt, local);
    __syncthreads();
    if (t == 0) *flag = (cnt >= 1200) ? 0 : 1;
}

// ---------------- K1: QKV projections (scalar, pipelined) ----------------------
// Q,K: [h][b][n][c64] (c contig);  V: [h][b][c64][n] (n contig)
__global__ void k_qkv(
    const u16* __restrict__ x1, const u16* __restrict__ x2,
    const u16* __restrict__ Wq, const u16* __restrict__ bq,
    const u16* __restrict__ Wk, const u16* __restrict__ bk,
    const u16* __restrict__ Wv, const u16* __restrict__ bv,
    u16* __restrict__ Qg, u16* __restrict__ Kg, u16* __restrict__ Vg,
    const int* __restrict__ flag)
{
    const int f32 = *flag;
    int id = blockIdx.x;
    int proj = id >> 8;            // 0=q,1=k,2=v
    int rem  = id & 255;
    int b  = rem >> 5;
    int ot = (rem >> 2) & 7;       // o-tile (64 outputs = 8 c x 8 h)
    int nt = rem & 3;              // n-tile (64 tokens)

    const u16* X    = (proj == 0) ? x1 : x2;
    const u16* W    = (proj == 0) ? Wq : (proj == 1) ? Wk : Wv;
    const u16* bias = (proj == 0) ? bq : (proj == 1) ? bk : bv;

    __shared__ float Ws[64][68];   // stage: Ws[i][o]; epilogue: Ls[o_local][n_local]
    __shared__ float Xs[64][64];   // Xs[i][n]

    int t = threadIdx.x;
    int lane64 = t & 63;
    int quad   = t >> 6;
    int og = t >> 4;
    int ng = t & 15;

    float acc[16];
#pragma unroll
    for (int j = 0; j < 16; ++j) acc[j] = 0.f;

    float wreg[16], xreg[16];
#pragma unroll
    for (int p = 0; p < 16; ++p) {
        int o = quad + 4*p;
        wreg[p] = ld(W, (size_t)(ot*64 + o)*CIN + 0*64 + lane64, f32);
    }
#pragma unroll
    for (int p = 0; p < 16; ++p) {
        int i = quad + 4*p;
        xreg[p] = ld(X, ((size_t)b*CIN + 0*64 + i)*NT + nt*64 + lane64, f32);
    }

    for (int kc = 0; kc < 4; ++kc) {
        __syncthreads();
#pragma unroll
        for (int p = 0; p < 16; ++p)
            Ws[lane64][quad + 4*p] = wreg[p];
#pragma unroll
        for (int p = 0; p < 16; ++p)
            Xs[quad + 4*p][lane64] = xreg[p];
        __syncthreads();

        if (kc < 3) {
            int kn = kc + 1;
#pragma unroll
            for (int p = 0; p < 16; ++p) {
                int o = quad + 4*p;
                wreg[p] = ld(W, (size_t)(ot*64 + o)*CIN + kn*64 + lane64, f32);
            }
#pragma unroll
            for (int p = 0; p < 16; ++p) {
                int i = quad + 4*p;
                xreg[p] = ld(X, ((size_t)b*CIN + kn*64 + i)*NT + nt*64 + lane64, f32);
            }
        }

#pragma unroll 8
        for (int i = 0; i < 64; ++i) {
            float4 w4 = *(const float4*)&Ws[i][og*4];
            float4 x4 = *(const float4*)&Xs[i][ng*4];
            FMA44(acc, 4, w4, x4);
        }
    }
    __syncthreads();

    // ---- epilogue ----
#pragma unroll
    for (int jo = 0; jo < 4; ++jo) {
        int o = ot*64 + og*4 + jo;
        float bb = ld(bias, o, f32);
#pragma unroll
        for (int jn = 0; jn < 4; ++jn)
            Ws[og*4 + jo][ng*4 + jn] = acc[jo*4 + jn] + bb;
    }
    __syncthreads();

    if (proj < 2) {
        u16* OUT = (proj == 0) ? Qg : Kg;
        int hh = t >> 5;
        int nb = t & 31;
#pragma unroll
        for (int p = 0; p < 2; ++p) {
            int nn = nb + 32*p;
            u32 pk[4];
#pragma unroll
            for (int e = 0; e < 4; ++e) {
                u16 lo = f2bf(Ws[(2*e  )*8 + hh][nn]);
                u16 hi = f2bf(Ws[(2*e+1)*8 + hh][nn]);
                pk[e] = (u32)lo | ((u32)hi << 16);
            }
            U32x4 v; v.x = pk[0]; v.y = pk[1]; v.z = pk[2]; v.w = pk[3];
            *(U32x4*)&OUT[((size_t)((hh*8 + b)*256) + nt*64 + nn)*64 + ot*8] = v;
        }
    } else {
        int rr = t >> 2;
        int hh = rr & 7, cl = rr >> 3;
        int nq = t & 3;
        u32 pk[8];
#pragma unroll
        for (int e = 0; e < 8; ++e) {
            u16 lo = f2bf(Ws[cl*8 + hh][nq*16 + 2*e  ]);
            u16 hi = f2bf(Ws[cl*8 + hh][nq*16 + 2*e+1]);
            pk[e] = (u32)lo | ((u32)hi << 16);
        }
        size_t base = ((size_t)((hh*8 + b)*64) + ot*8 + cl)*256 + nt*64 + nq*16;
        U32x4 v0; v0.x = pk[0]; v0.y = pk[1]; v0.z = pk[2]; v0.w = pk[3];
        U32x4 v1; v1.x = pk[4]; v1.y = pk[5]; v1.z = pk[6]; v1.w = pk[7];
        *(U32x4*)&Vg[base]     = v0;
        *(U32x4*)&Vg[base + 8] = v1;
    }
}

// ---------------- K2: cross-batch attention, MFMA 16x16x32 bf16 ----------------
// ONLY kernel changed this round (in-place, values identical):
//  (a) K LDS layout bank-swizzle: pos = qs*16 + (klo ^ (qs&1)*2 ^ kc*4).
//      Old pattern put 8 lanes per quarter-wave on one 4-bank set; new is
//      balanced (2/set = free). Readers un-XOR via lswz2/(^4).
//  (b) V swizzle gains ^ (qs&1)*4 (4-way -> 2-way), readers match.
//  (c) P round-trip writes packed as u32 pairs (32 stores vs 64).
__global__ __launch_bounds__(256) void k_attn(
    const u16* __restrict__ Qg, const u16* __restrict__ Kg,
    const u16* __restrict__ Vg, float* __restrict__ Oph)
{
    int bid = blockIdx.x;
    int h   = bid >> 5;
    int b   = (bid >> 2) & 7;
    int ntq = bid & 3;

    int t = threadIdx.x;
    int l = t & 63, w = t >> 6;
    int quad = l >> 4, col = l & 15;

    __shared__ __align__(16) u16 S[16896];   // 33 KB, phases: K | P(stride 66) | V

    int q = ntq*64 + w*16 + col;
    const size_t qrow = ((size_t)(h*8 + b)*256 + q)*64;
    bf16x8 qf0 = *(const bf16x8*)&Qg[qrow +  0 + quad*8];
    bf16x8 qf1 = *(const bf16x8*)&Qg[qrow + 32 + quad*8];

    const int lswz2 = l ^ (((l >> 4) & 1) << 1);   // K read un-swizzle
    const int lswz4 = l ^ (((l >> 4) & 1) << 2);   // V read un-swizzle (pre ^ch)

    f32x4 Oacc[4];
#pragma unroll
    for (int ct = 0; ct < 4; ++ct) { Oacc[ct][0]=0.f; Oacc[ct][1]=0.f; Oacc[ct][2]=0.f; Oacc[ct][3]=0.f; }

    for (int kb = 0; kb < 8; ++kb) {
        __syncthreads();                                   // prev PV reads done
        // ---- stage K (8 iters x 256 thr), bank-swizzled ----
        const size_t kbase = (size_t)(h*8 + kb) * 256 * 64;
#pragma unroll
        for (int i = 0; i < 8; ++i) {
            int g = i*256 + t;
            int key = g >> 3, cc = g & 7;
            int tt = key >> 4, klo = key & 15, kc = cc >> 2, qs = cc & 3;
            int pos = qs*16 + (klo ^ ((qs & 1) << 1) ^ (kc << 2));
            U32x4 v = *(const U32x4*)&Kg[kbase + (size_t)key*64 + cc*8];
            *(U32x4*)&S[(size_t)(((tt*2 + kc)*64) + pos)*8] = v;
        }
        __syncthreads();

        // ---- QK^T ----
        f32x4 Sfr[16];
#pragma unroll
        for (int tt = 0; tt < 16; ++tt) { Sfr[tt][0]=0.f; Sfr[tt][1]=0.f; Sfr[tt][2]=0.f; Sfr[tt][3]=0.f; }
#pragma unroll
        for (int tt = 0; tt < 16; ++tt) {
            bf16x8 k0 = *(const bf16x8*)&S[(size_t)((tt*2 + 0)*64 + lswz2)*8];
            bf16x8 k1 = *(const bf16x8*)&S[(size_t)((tt*2 + 1)*64 + (lswz2 ^ 4))*8];
            Sfr[tt] = __builtin_amdgcn_mfma_f32_16x16x32_bf16(qf0, k0, Sfr[tt], 0, 0, 0);
            Sfr[tt] = __builtin_amdgcn_mfma_f32_16x16x32_bf16(qf1, k1, Sfr[tt], 0, 0, 0);
        }

        // ---- exact softmax per q-row ----
        float inv[4];
#pragma unroll
        for (int r = 0; r < 4; ++r) {
            float m = Sfr[0][r];
#pragma unroll
            for (int tt = 1; tt < 16; ++tt) m = fmaxf(m, Sfr[tt][r]);
#pragma unroll
            for (int off = 1; off < 16; off <<= 1) m = fmaxf(m, __shfl_xor(m, off));
            float s = 0.f;
#pragma unroll
            for (int tt = 0; tt < 16; ++tt) {
                float e = __expf(Sfr[tt][r] - m);
                Sfr[tt][r] = e; s += e;
            }
#pragma unroll
            for (int off = 1; off < 16; off <<= 1) s += __shfl_xor(s, off);
            inv[r] = 1.f / s;
        }
        __syncthreads();                                   // all K reads done

        // ---- P: C-layout -> LDS [key][q64], stride 66 u16, packed u32 ----
#pragma unroll
        for (int tt = 0; tt < 16; ++tt)
#pragma unroll
            for (int e = 0; e < 2; ++e) {
                u32 pk = (u32)f2bf(Sfr[tt][2*e]   * inv[2*e]) |
                        ((u32)f2bf(Sfr[tt][2*e+1] * inv[2*e+1]) << 16);
                *(u32*)&S[(tt*16 + col)*66 + w*16 + quad*4 + 2*e] = pk;
            }

        bf16x8 pf[8];
#pragma unroll
        for (int ch = 0; ch < 8; ++ch)
#pragma unroll
            for (int j = 0; j < 8; ++j)
                pf[ch][j] = (short)S[(ch*32 + quad*8 + j)*66 + w*16 + col];
        __syncthreads();                                   // all P reads done

        // ---- stage V (swizzled, 8 iters x 256 thr) ----
        const size_t vbase = (size_t)(h*8 + kb) * 64 * 256;
#pragma unroll
        for (int i = 0; i < 8; ++i) {
            int g = i*256 + t;
            int cg = g >> 5, k16 = g & 31;
            int ct = cg >> 4, clo = cg & 15, ch = k16 >> 2, qs = k16 & 3;
            int pos = (qs*16 + clo) ^ ch ^ ((qs & 1) << 2);
            U32x4 v = *(const U32x4*)&Vg[vbase + (size_t)cg*256 + k16*8];
            *(U32x4*)&S[(size_t)(((ch*4 + ct)*64) + pos)*8] = v;
        }
        __syncthreads();

        // ---- PV ----
#pragma unroll
        for (int ch = 0; ch < 8; ++ch)
#pragma unroll
            for (int ct = 0; ct < 4; ++ct) {
                bf16x8 vb = *(const bf16x8*)&S[(size_t)(((ch*4 + ct)*64) + (lswz4 ^ ch))*8];
                Oacc[ct] = __builtin_amdgcn_mfma_f32_16x16x32_bf16(pf[ch], vb, Oacc[ct], 0, 0, 0);
            }
    }

    // ---- write O: Oph[h][b][n][c] fp32 ----
    const size_t obase = (size_t)(h*8 + b) * 256 * 64;
    int n0 = ntq*64 + w*16 + quad*4;
#pragma unroll
    for (int ct = 0; ct < 4; ++ct)
#pragma unroll
        for (int r = 0; r < 4; ++r)
            Oph[obase + (size_t)(n0 + r)*64 + ct*16 + col] = Oacc[ct][r];
}

// ---------------- K3: Wa projection + bias + residual (scalar, pipelined) ------
__global__ void k_proj_res(
    const float* __restrict__ Oph, const u16* __restrict__ Wa,
    const u16* __restrict__ ba, const u16* __restrict__ x1,
    float* __restrict__ Ap, const int* __restrict__ flag)
{
    const int f32 = *flag;
    int id = blockIdx.x;
    int tt = id >> 2;           // 0..63 (32-token tiles)
    int it = id & 3;            // i tile 0..3
    int tok0 = tt * 32;
    int b  = tok0 >> 8;
    int n0 = tok0 & 255;

    __shared__ float Was[64][68];  // Was[o][i]
    __shared__ float Os[64][36];   // Os[o][tok32]

    int t = threadIdx.x;
    int lane64 = t & 63, quad = t >> 6;
    int ig = t & 15;
    int tg = t >> 4;

    int tk = t & 31;
    int hh = t >> 5;

    float wreg[16];
    float oreg[8];

    {
#pragma unroll
        for (int p = 0; p < 16; ++p) {
            int i = quad + 4*p;
            wreg[p] = ld(Wa, (size_t)(it*64 + i)*EMB + 0*64 + lane64, f32);
        }
        const float* src = &Oph[(((size_t)(hh*8 + b))*256 + n0 + tk)*64 + 0*8];
        float4 v0 = *(const float4*)&src[0];
        float4 v1 = *(const float4*)&src[4];
        oreg[0]=v0.x; oreg[1]=v0.y; oreg[2]=v0.z; oreg[3]=v0.w;
        oreg[4]=v1.x; oreg[5]=v1.y; oreg[6]=v1.z; oreg[7]=v1.w;
    }

    float acc[8];
#pragma unroll
    for (int j = 0; j < 8; ++j) acc[j] = 0.f;

    for (int kc = 0; kc < 8; ++kc) {
        __syncthreads();
#pragma unroll
        for (int p = 0; p < 16; ++p)
            Was[lane64][quad + 4*p] = wreg[p];
#pragma unroll
        for (int e = 0; e < 8; ++e)
            Os[e*8 + hh][tk] = oreg[e];
        __syncthreads();

        if (kc < 7) {
            int kn = kc + 1;
#pragma unroll
            for (int p = 0; p < 16; ++p) {
                int i = quad + 4*p;
                wreg[p] = ld(Wa, (size_t)(it*64 + i)*EMB + kn*64 + lane64, f32);
            }
            const float* src = &Oph[(((size_t)(hh*8 + b))*256 + n0 + tk)*64 + kn*8];
            float4 v0 = *(const float4*)&src[0];
            float4 v1 = *(const float4*)&src[4];
            oreg[0]=v0.x; oreg[1]=v0.y; oreg[2]=v0.z; oreg[3]=v0.w;
            oreg[4]=v1.x; oreg[5]=v1.y; oreg[6]=v1.z; oreg[7]=v1.w;
        }

#pragma unroll 8
        for (int o = 0; o < 64; ++o) {
            float4 w4 = *(const float4*)&Was[o][ig*4];
            float2 t2 = *(const float2*)&Os[o][tg*2];
            acc[0] += w4.x*t2.x; acc[1] += w4.y*t2.x;
            acc[2] += w4.z*t2.x; acc[3] += w4.w*t2.x;
            acc[4] += w4.x*t2.y; acc[5] += w4.y*t2.y;
            acc[6] += w4.z*t2.y; acc[7] += w4.w*t2.y;
        }
    }

    int i0 = it*64 + ig*4;
    float ba0 = ld(ba, i0+0, f32), ba1 = ld(ba, i0+1, f32);
    float ba2 = ld(ba, i0+2, f32), ba3 = ld(ba, i0+3, f32);
#pragma unroll
    for (int jt = 0; jt < 2; ++jt) {
        int token = tok0 + tg*2 + jt;
        int n = n0 + tg*2 + jt;
        float4 v;
        v.x = acc[jt*4+0] + ba0 + ld(x1, ((size_t)b*CIN + i0+0)*NT + n, f32);
        v.y = acc[jt*4+1] + ba1 + ld(x1, ((size_t)b*CIN + i0+1)*NT + n, f32);
        v.z = acc[jt*4+2] + ba2 + ld(x1, ((size_t)b*CIN + i0+2)*NT + n, f32);
        v.w = acc[jt*4+3] + ba3 + ld(x1, ((size_t)b*CIN + i0+3)*NT + n, f32);
        *(float4*)&Ap[(size_t)token*CIN + i0] = v;
    }
}

// ---------------- K4: LayerNorm + Linear + ReLU -> out -------------------------
__global__ void k_ln_out(
    const float* __restrict__ Ap, const u16* __restrict__ ln_g,
    const u16* __restrict__ ln_b, const u16* __restrict__ Wl,
    const u16* __restrict__ bl, u16* __restrict__ out,
    const int* __restrict__ flag)
{
    const int f32 = *flag;
    int tok0 = blockIdx.x * 8;
    int b  = tok0 >> 8;
    int n0 = tok0 & 255;

    __shared__ float At[8][260];

    int t = threadIdx.x;
#pragma unroll
    for (int k = 0; k < 8; ++k)
        At[k][t] = Ap[((size_t)tok0 + k)*CIN + t];
    __syncthreads();

    {   // LN: 32 lanes per token, 8 i-values each
        int kk = t >> 5, lme = t & 31;
        float s = 0.f, s2 = 0.f;
#pragma unroll
        for (int ii = 0; ii < 8; ++ii) { float v = At[kk][lme + 32*ii]; s += v; s2 += v*v; }
#pragma unroll
        for (int off = 1; off < 32; off <<= 1) { s += __shfl_xor(s, off); s2 += __shfl_xor(s2, off); }
        float mu   = s  * (1.f/256.f);
        float var  = s2 * (1.f/256.f) - mu*mu;
        float rstd = rsqrtf(var + 1e-5f);
#pragma unroll
        for (int ii = 0; ii < 8; ++ii) {
            int i = lme + 32*ii;
            float v = At[kk][i];
            At[kk][i] = (v - mu) * rstd * ld(ln_g, i, f32) + ld(ln_b, i, f32);
        }
    }
    __syncthreads();

    int j = t;
    float acc[8];
#pragma unroll
    for (int k = 0; k < 8; ++k) acc[k] = 0.f;

    if (f32) {
        const float* wrow = (const float*)Wl + (size_t)j*CIN;
#pragma unroll 2
        for (int i4 = 0; i4 < 64; ++i4) {
            float4 w4 = *(const float4*)&wrow[4*i4];
#pragma unroll
            for (int k = 0; k < 8; ++k) {
                float4 a = *(const float4*)&At[k][4*i4];
                acc[k] += w4.x*a.x + w4.y*a.y + w4.z*a.z + w4.w*a.w;
            }
        }
    } else {
        const u32* wrow = (const u32*)(Wl + (size_t)j*CIN);
#pragma unroll 2
        for (int i4 = 0; i4 < 64; ++i4) {
            u32 w01 = wrow[2*i4+0], w23 = wrow[2*i4+1];
            float c0 = bf2f((u16)(w01 & 0xFFFFu)), c1 = bf2f((u16)(w01 >> 16));
            float c2 = bf2f((u16)(w23 & 0xFFFFu)), c3 = bf2f((u16)(w23 >> 16));
#pragma unroll
            for (int k = 0; k < 8; ++k) {
                float4 a = *(const float4*)&At[k][4*i4];
                acc[k] += c0*a.x + c1*a.y + c2*a.z + c3*a.w;
            }
        }
    }

    float blv = ld(bl, j, f32);
    size_t obase = ((size_t)b*CIN + j)*NT + n0;
    if (f32) {
        float* o32 = (float*)out;
#pragma unroll
        for (int k = 0; k < 8; ++k)
            o32[obase + k] = fmaxf(acc[k] + blv, 0.f);
    } else {
        u32 pk[4];
#pragma unroll
        for (int k = 0; k < 4; ++k) {
            float f0 = fmaxf(acc[2*k+0] + blv, 0.f);
            float f1 = fmaxf(acc[2*k+1] + blv, 0.f);
            pk[k] = (u32)f2bf(f0) | ((u32)f2bf(f1) << 16);
        }
        U32x4 a0; a0.x = pk[0]; a0.y = pk[1]; a0.z = pk[2]; a0.w = pk[3];
        *(U32x4*)(out + obase) = a0;
    }
}

// ---------------------------------------------------------------
extern "C" void kernel_launch(void* const* d_in, const int* in_sizes, int n_in,
                              void* d_out, int out_size, void* d_ws, size_t ws_size,
                              hipStream_t stream)
{
    const u16* x1   = (const u16*)d_in[0];
    const u16* x2   = (const u16*)d_in[1];
    const u16* Wq   = (const u16*)d_in[2];
    const u16* bq   = (const u16*)d_in[3];
    const u16* Wk   = (const u16*)d_in[4];
    const u16* bk   = (const u16*)d_in[5];
    const u16* Wv   = (const u16*)d_in[6];
    const u16* bv   = (const u16*)d_in[7];
    const u16* Wa   = (const u16*)d_in[8];
    const u16* ba   = (const u16*)d_in[9];
    const u16* ln_g = (const u16*)d_in[10];
    const u16* ln_b = (const u16*)d_in[11];
    const u16* Wl   = (const u16*)d_in[12];
    const u16* bl   = (const u16*)d_in[13];
    u16* out = (u16*)d_out;

    int* flag = (int*)d_ws;
    u16* Qg = (u16*)d_ws + 32;                    // +64 B
    u16* Kg = Qg + (size_t)BB*EMB*NT;             // 1M u16 each
    u16* Vg = Kg + (size_t)BB*EMB*NT;
    float* Oph = (float*)(Vg + (size_t)BB*EMB*NT);
    float* Ap  = Oph + (size_t)BB*EMB*NT;

    k_detect  <<<1,   256, 0, stream>>>(x1, flag);
    k_qkv     <<<768, 256, 0, stream>>>(x1, x2, Wq, bq, Wk, bk, Wv, bv, Qg, Kg, Vg, flag);
    k_attn    <<<256, 256, 0, stream>>>(Qg, Kg, Vg, Oph);
    k_proj_res<<<256, 256, 0, stream>>>(Oph, Wa, ba, x1, Ap, flag);
    k_ln_out  <<<256, 256, 0, stream>>>(Ap, ln_g, ln_b, Wl, bl, out, flag);
}